// Round 2
// baseline (181.583 us; speedup 1.0000x reference)
//
#include <hip/hip_runtime.h>

// CTC batch cost (Keras ctc_batch_cost, full lengths).
// B=64, T=2048, C=128 (blank=127), L=256, S=513.
//
// Round-14: DEFERRED-EPS + ROLLED RING. R13 (fwd/bwd split) scaled exactly
// 2x from R12 -> the ~150 cyc/step stall is per-wave intrinsic. Theory: the
// fill()'s "+EPSF" adds consume the 5 gathers immediately, putting the
// lgkmcnt wait right after the ds_reads (~120 cyc exposed latency/step).
// Changes:
//  (1) fill is now PURE ds_read (raw into G); +EPSF moved into step(), one
//      group (~4 steps) after the load -> LDS latency fully hidden.
//  (2) generic rolled 4-step group over a 64-row circular ring (roff +=
//      2048 & 32767 per group); row-in-group stays compile-time k*512 in
//      the ds_read imm, so R12's addr-VALU diet survives (+7 VALU/group).
//      Hot code shrinks ~75KB -> ~10KB per direction.
//  (3) backward DMA places each 2-row block reversed (dst 7168 - i*1024),
//      so bwd fills use roff + (k^1)*512 with the same roff recurrence.
// Unchanged: WAIT_VM(8) never-drain vmcnt discipline, block-float linear
// numerics with exponent renorm every 4 steps + DPP neighbor adoption,
// fwd/bwd meet at t=1023/1024 with a 9-FMA dot + 64-lane logsumexp.

#define B_ 64
#define T_ 2048
#define C_ 128
#define L_ 256
#define BLANK_ (C_ - 1)
#define EPSF 1e-7f
#define LN2F 0.69314718055994530942f
#define CH_ 16
#define SENT_ (-(1 << 28))    // "lane is all-zero" exponent sentinel

typedef __attribute__((address_space(1))) const void glob_cv;
typedef __attribute__((address_space(3))) void lds_v;

__device__ __forceinline__ void gl2lds16(const void* g, void* l) {
    __builtin_amdgcn_global_load_lds((glob_cv*)g, (lds_v*)l, 16, 0, 0);
}

#define WAIT_VM(n) asm volatile("s_waitcnt vmcnt(" #n ")" ::: "memory")

// lane l -> value of lane l-1; lane 0 -> 0. DPP ctrl 0x138 = wave_shr:1.
__device__ __forceinline__ float dpp_shr1_f(float x) {
    return __int_as_float(
        __builtin_amdgcn_update_dpp(0, __float_as_int(x), 0x138, 0xf, 0xf, false));
}
__device__ __forceinline__ int dpp_shr1_i(int x) {
    return __builtin_amdgcn_update_dpp(0, x, 0x138, 0xf, 0xf, false);
}
// lane l -> value of lane l+1; lane 63 -> 0. DPP ctrl 0x130 = wave_shl:1.
__device__ __forceinline__ float dpp_shl1_f(float x) {
    return __int_as_float(
        __builtin_amdgcn_update_dpp(0, __float_as_int(x), 0x130, 0xf, 0xf, false));
}
__device__ __forceinline__ int dpp_shl1_i(int x) {
    return __builtin_amdgcn_update_dpp(0, x, 0x130, 0xf, 0xf, false);
}

struct G { float pb, p1, p3, p5, p7; };  // RAW lds values (EPSF added at use)

__launch_bounds__(128, 1)
__global__ void ctc_loss_kernel(const int* __restrict__ y_true,
                                const float* __restrict__ y_pred,
                                float* __restrict__ out) {
    const int b = blockIdx.x;
    const int tid = threadIdx.x;
    const int w = __builtin_amdgcn_readfirstlane(tid >> 6);  // 0=fwd, 1=bwd
    const int l = tid & 63;

    __shared__ float ring[2][8192];  // per-wave 64-row x 128-col circular, 32KB

    const int* __restrict__ lab = y_true + b * L_;
    const int4 lv = *(const int4*)(lab + 4 * l);   // labels 4l..4l+3
    const int e1 = lv.x, e3 = lv.y, e5 = lv.z, e7 = lv.w;
    const int em1 = (l > 0) ? lab[4 * l - 1] : -1;
    const float m1f = ((l > 0) && (e1 != em1)) ? 1.0f : 0.0f;  // skip gates
    const float m3f = (e3 != e1) ? 1.0f : 0.0f;
    const float m5f = (e5 != e3) ? 1.0f : 0.0f;
    const float m7f = (e7 != e5) ? 1.0f : 0.0f;
    const float m8f = (l == 63) ? 1.0f : 0.0f;     // state-512 coupling gate

    const float* __restrict__ base = y_pred + (size_t)b * (T_ * C_);

    char* const lds0 = (char*)&ring[0][0];
    const int rbase = w * 32768;
    const int cBo = rbase + BLANK_ * 4;   // per-lane column byte offsets
    const int c1o = rbase + e1 * 4;
    const int c3o = rbase + e3 * 4;
    const int c5o = rbase + e5 * 4;
    const int c7o = rbase + e7 * 4;

#define LDF(o) (*(const float*)(lds0 + (o)))

    G g[4];  // lookahead-4 slots; slot index always compile-time
    float a0 = 0.f, a1 = 0.f, a2 = 0.f, a3 = 0.f, a4 = 0.f,
          a5 = 0.f, a6 = 0.f, a7 = 0.f, a8 = 0.f;
    int E = SENT_;
    float upscale = 1.0f;  // 2^(E_nbr - E), fixed within a 4-step window
    int roff = 0;          // fill base byte offset within ring (group-level)
    int ldso = 0;          // next DMA dest byte offset within ring
    const char* gptr;      // next DMA global src (per-lane)

    auto fillRow = [&](int slot, int row) {  // prologue only (row imm)
        const int ro = row * 512;
        g[slot].pb = LDF(cBo + ro);
        g[slot].p1 = LDF(c1o + ro);
        g[slot].p3 = LDF(c3o + ro);
        g[slot].p5 = LDF(c5o + ro);
        g[slot].p7 = LDF(c7o + ro);
    };

    // ---------------- forward machinery (wave 0) ----------------
    auto step = [&](const G& q) {
        const float pb = q.pb + EPSF, p1 = q.p1 + EPSF, p3 = q.p3 + EPSF,
                    p5 = q.p5 + EPSF, p7 = q.p7 + EPSF;
        const float up = dpp_shr1_f(a7) * upscale;  // state 8l-1, rescaled
        const float n0 = (a0 + up) * pb;
        const float n1 = fmaf(m1f, up, a0 + a1) * p1;
        const float n2 = (a1 + a2) * pb;
        const float n3 = fmaf(m3f, a1, a2 + a3) * p3;
        const float n4 = (a3 + a4) * pb;
        const float n5 = fmaf(m5f, a3, a4 + a5) * p5;
        const float n6 = (a5 + a6) * pb;
        const float n7 = fmaf(m7f, a5, a6 + a7) * p7;
        const float n8 = fmaf(m8f, a7, a8) * pb;    // state 512
        a0 = n0; a1 = n1; a2 = n2; a3 = n3; a4 = n4;
        a5 = n5; a6 = n6; a7 = n7; a8 = n8;
    };

    auto boundary = [&]() {
        float mx = fmaxf(fmaxf(fmaxf(a0, a1), fmaxf(a2, a3)),
                         fmaxf(fmaxf(a4, a5), fmaxf(a6, a7)));
        mx = fmaxf(mx, a8);
        const bool z = (mx == 0.0f);
        const int e = (int)(__float_as_uint(mx) >> 23) - 127;
        const float s = z ? 1.0f : __uint_as_float((unsigned)(127 - e) << 23);
        a0 *= s; a1 *= s; a2 *= s; a3 *= s; a4 *= s;
        a5 *= s; a6 *= s; a7 *= s; a8 *= s;
        E = z ? SENT_ : (E + e);
        int upE = dpp_shr1_i(E);
        if (l == 0) upE = SENT_;
        if (E == SENT_) E = upE;            // adopt neighbor scale (exact)
        int d = upE - E;
        d = min(max(d, -126), 120);
        upscale = __uint_as_float((unsigned)(d + 127) << 23);
    };

    auto grpF = [&](bool dofill) {  // 4 steps; fills rows (roff/512)..+3
        roff = (roff + 2048) & 32767;
        const int oB = cBo + roff, o1 = c1o + roff, o3 = c3o + roff,
                  o5 = c5o + roff, o7 = c7o + roff;
#pragma unroll
        for (int k = 0; k < 4; ++k) {
            step(g[k]);
            if (dofill) {
                g[k].pb = LDF(oB + k * 512);
                g[k].p1 = LDF(o1 + k * 512);
                g[k].p3 = LDF(o3 + k * 512);
                g[k].p5 = LDF(o5 + k * 512);
                g[k].p7 = LDF(o7 + k * 512);
            }
        }
        boundary();
    };

    // ---------------- backward machinery (wave 1) ----------------
    auto stepb = [&](const G& q) {
        const float pb = q.pb + EPSF, p1 = q.p1 + EPSF, p3 = q.p3 + EPSF,
                    p5 = q.p5 + EPSF, p7 = q.p7 + EPSF;
        const float d0 = a0 * pb, d1 = a1 * p1, d2 = a2 * pb,
                    d3 = a3 * p3, d4 = a4 * pb, d5 = a5 * p5,
                    d6 = a6 * pb, d7 = a7 * p7, d8 = a8 * pb;
        const float u = fmaf(m1f, d1, d0);          // exported to lane l-1
        const float dn = dpp_shl1_f(u) * upscale;   // lane l+1's u, rescaled
        a0 = d0 + d1;
        a1 = fmaf(m3f, d3, d1 + d2);
        a2 = d2 + d3;
        a3 = fmaf(m5f, d5, d3 + d4);
        a4 = d4 + d5;
        a5 = fmaf(m7f, d7, d5 + d6);
        a6 = d6 + d7;
        a7 = fmaf(m8f, d8, d7 + dn);                // state 511 (+512 on l=63)
        a8 = d8;                                    // state 512
    };

    auto boundaryb = [&]() {
        float mx = fmaxf(fmaxf(fmaxf(a0, a1), fmaxf(a2, a3)),
                         fmaxf(fmaxf(a4, a5), fmaxf(a6, a7)));
        mx = fmaxf(mx, a8);
        const bool z = (mx == 0.0f);
        const int e = (int)(__float_as_uint(mx) >> 23) - 127;
        const float s = z ? 1.0f : __uint_as_float((unsigned)(127 - e) << 23);
        a0 *= s; a1 *= s; a2 *= s; a3 *= s; a4 *= s;
        a5 *= s; a6 *= s; a7 *= s; a8 *= s;
        E = z ? SENT_ : (E + e);
        int upE = dpp_shl1_i(E);            // neighbor is lane l+1
        if (l == 63) upE = SENT_;
        if (E == SENT_) E = upE;
        int d = upE - E;
        d = min(max(d, -126), 120);
        upscale = __uint_as_float((unsigned)(d + 127) << 23);
    };

    auto grpB = [&](bool dofill) {  // bwd rows are pair-reversed: (k^1)*512
        roff = (roff + 2048) & 32767;
        const int oB = cBo + roff, o1 = c1o + roff, o3 = c3o + roff,
                  o5 = c5o + roff, o7 = c7o + roff;
#pragma unroll
        for (int k = 0; k < 4; ++k) {
            stepb(g[k]);
            if (dofill) {
                const int ro = (k ^ 1) * 512;
                g[k].pb = LDF(oB + ro);
                g[k].p1 = LDF(o1 + ro);
                g[k].p3 = LDF(o3 + ro);
                g[k].p5 = LDF(o5 + ro);
                g[k].p7 = LDF(o7 + ro);
            }
        }
        boundaryb();
    };

    // ---------------- DMA staging ----------------
    auto issueF = [&]() {  // next chunk, forward row order
#pragma unroll
        for (int i = 0; i < 8; ++i)
            gl2lds16(gptr + i * 1024, lds0 + rbase + ldso + i * 1024);
        gptr += 8192;
        ldso = (ldso + 8192) & 32767;
    };
    auto issueB = [&]() {  // next chunk, 2-row blocks placed reversed
#pragma unroll
        for (int i = 0; i < 8; ++i)
            gl2lds16(gptr + i * 1024, lds0 + rbase + ldso + (7168 - i * 1024));
        gptr -= 8192;
        ldso = (ldso + 8192) & 32767;
    };

    if (w == 0) {
        // ======== forward: t = 0..1023 ========
        gptr = (const char*)(base + 4 * l);
        issueF(); issueF(); issueF();      // chunks 0,1,2
        WAIT_VM(8);                        // 0,1 landed; 2 in flight
        issueF();                          // chunk 3
        if (l == 0) { a0 = LDF(cBo) + EPSF; a1 = LDF(c1o) + EPSF; E = 0; }
        boundary();                        // seeds lane1's adoption of E
        fillRow(1, 1); fillRow(2, 2); fillRow(3, 3); fillRow(0, 4);
        step(g[1]); fillRow(1, 5);         // t=1..3
        step(g[2]); fillRow(2, 6);
        step(g[3]); fillRow(3, 7);
        boundary();
        roff = 2048;                       // group 1 fills rows 8..11
#pragma unroll 1
        for (int gg = 0; gg < 3; ++gg) grpF(true);   // chunk 0 rest
#pragma unroll 1
        for (int c = 1; c <= 60; ++c) {
            WAIT_VM(8);
            issueF();                      // chunk c+3
#pragma unroll 1
            for (int gg = 0; gg < 4; ++gg) grpF(true);
        }
        WAIT_VM(8);
#pragma unroll 1
        for (int gg = 0; gg < 4; ++gg) grpF(true);   // chunk 61
        WAIT_VM(0);
#pragma unroll 1
        for (int gg = 0; gg < 4; ++gg) grpF(true);   // chunk 62
#pragma unroll 1
        for (int gg = 0; gg < 3; ++gg) grpF(true);   // chunk 63
        grpF(false);
        // a0..a8, E now hold alpha_{1023}
    } else {
        // ======== backward: t = 2047..1024 (q = 0..1023) ========
        gptr = (const char*)(base + 127 * CH_ * C_ + 4 * l);
        issueB(); issueB(); issueB();      // qc 0,1,2 (global 127,126,125)
        WAIT_VM(8);
        issueB();                          // qc 3
        if (l == 63) { a7 = 1.0f; a8 = 1.0f; E = 0; }  // c_2048 = f
        boundaryb();                       // seeds lane62's adoption of E
        // slots 0..3 <- q=0..3 (lds rows 1,0,3,2 of buf 0)
        fillRow(0, 1); fillRow(1, 0); fillRow(2, 3); fillRow(3, 2);
        roff = 0;                          // group 0 fills q'=4..7 @ 2048
#pragma unroll 1
        for (int gg = 0; gg < 4; ++gg) grpB(true);   // chunk 0
#pragma unroll 1
        for (int c = 1; c <= 60; ++c) {
            WAIT_VM(8);
            issueB();                      // qc c+3
#pragma unroll 1
            for (int gg = 0; gg < 4; ++gg) grpB(true);
        }
        WAIT_VM(8);
#pragma unroll 1
        for (int gg = 0; gg < 4; ++gg) grpB(true);   // qc 61
        WAIT_VM(0);
#pragma unroll 1
        for (int gg = 0; gg < 4; ++gg) grpB(true);   // qc 62
#pragma unroll 1
        for (int gg = 0; gg < 3; ++gg) grpB(true);   // qc 63
        grpB(false);
        // a0..a8, E now hold c_{1024}; export via own ring (drained)
        float* xf = &ring[1][0];
        xf[0 * 64 + l] = a0; xf[1 * 64 + l] = a1; xf[2 * 64 + l] = a2;
        xf[3 * 64 + l] = a3; xf[4 * 64 + l] = a4; xf[5 * 64 + l] = a5;
        xf[6 * 64 + l] = a6; xf[7 * 64 + l] = a7; xf[8 * 64 + l] = a8;
        ((int*)xf)[9 * 64 + l] = E;
    }

    __syncthreads();

    if (w == 0) {
        // p = <alpha_{1023}, c_{1024}>: lane dot then 64-lane logsumexp.
        const float* xf = &ring[1][0];
        float sd = a0 * xf[0 * 64 + l];
        sd = fmaf(a1, xf[1 * 64 + l], sd);
        sd = fmaf(a2, xf[2 * 64 + l], sd);
        sd = fmaf(a3, xf[3 * 64 + l], sd);
        sd = fmaf(a4, xf[4 * 64 + l], sd);
        sd = fmaf(a5, xf[5 * 64 + l], sd);
        sd = fmaf(a6, xf[6 * 64 + l], sd);
        sd = fmaf(a7, xf[7 * 64 + l], sd);
        sd = fmaf(a8, xf[8 * 64 + l], sd);
        const int E2 = ((const int*)xf)[9 * 64 + l];
        const bool nz = (sd > 0.0f);
        int Es = nz ? (E + E2) : SENT_;
        int M = Es;
#pragma unroll
        for (int o = 32; o; o >>= 1) M = max(M, __shfl_xor(M, o));
        int d = Es - M;
        d = max(d, -126);
        float val = nz ? sd * __uint_as_float((unsigned)(d + 127) << 23) : 0.0f;
#pragma unroll
        for (int o = 32; o; o >>= 1) val += __shfl_xor(val, o);
        if (l == 0) out[b] = -(__logf(val) + (float)M * LN2F);
    }
}

extern "C" void kernel_launch(void* const* d_in, const int* in_sizes, int n_in,
                              void* d_out, int out_size, void* d_ws, size_t ws_size,
                              hipStream_t stream) {
    const int* y_true = (const int*)d_in[0];
    const float* y_pred = (const float*)d_in[1];
    float* out = (float*)d_out;
    ctc_loss_kernel<<<B_, 128, 0, stream>>>(y_true, y_pred, out);
}

// Round 3
// 179.814 us; speedup vs baseline: 1.0098x; 1.0098x over previous
//
#include <hip/hip_runtime.h>

// CTC batch cost (Keras ctc_batch_cost, full lengths).
// B=64, T=2048, C=128 (blank=127), L=256, S=513.
//
// Round-15: INVISIBLE LDS READS (counted lgkmcnt + asm ds_read).
// R12/R13/R14 all pin at ~240 cyc/step across totally different code
// shapes; VALU issue explains only ~90. Theory: LLVM's waitcnt pass
// treats global_load_lds as a VMEM op that writes LDS (mayWriteLDSThrough-
// DMA); every compiler-visible ds_read from `ring` may alias it, so the
// compiler inserts s_waitcnt vmcnt(0) before EVERY fill bundle - silently
// draining the 3-chunk prefetch and exposing a loaded-HBM round trip per
// chunk. Fix: hot-loop gathers are volatile inline-asm ds_read_b32 with
// addrspace(3) base pointers and compile-time offset: immediates (the
// compiler sees no LDS reads -> emits no vmcnt waits); LDS latency is
// handled by hand-counted s_waitcnt lgkmcnt(15) per step (20 reads in
// flight, oldest 5 must land; ladder 15/10/5/0 in the final chunk), each
// followed by sched_barrier(0) so consumers can't hoist above the wait
// (guide rule #18). WAIT_VM(8) is now the ONLY vmcnt discipline, as
// designed. Structure otherwise identical to R13 (fwd/bwd split, fully
// unrolled chunks, compile-time offsets); R14's deferred-EPS kept.

#define B_ 64
#define T_ 2048
#define C_ 128
#define L_ 256
#define BLANK_ (C_ - 1)
#define EPSF 1e-7f
#define LN2F 0.69314718055994530942f
#define CH_ 16
#define SENT_ (-(1 << 28))    // "lane is all-zero" exponent sentinel

typedef __attribute__((address_space(1))) const void glob_cv;
typedef __attribute__((address_space(3))) void lds_v;
typedef __attribute__((address_space(3))) float lds_f;

__device__ __forceinline__ void gl2lds16(const void* g, void* l) {
    __builtin_amdgcn_global_load_lds((glob_cv*)g, (lds_v*)l, 16, 0, 0);
}

#define WAIT_VM(n) asm volatile("s_waitcnt vmcnt(" #n ")" ::: "memory")
#define WAIT_LGKM(n) do { \
    asm volatile("s_waitcnt lgkmcnt(" #n ")" ::: "memory"); \
    __builtin_amdgcn_sched_barrier(0); } while (0)
// Volatile asm ds_read: invisible to the waitcnt pass; order among
// volatile asm (reads, WAIT_VM, WAIT_LGKM) is program order.
#define DSR(dst, p, off) \
    asm volatile("ds_read_b32 %0, %1 offset:%2" : "=v"(dst) : "v"(p), "i"(off))

// lane l -> value of lane l-1; lane 0 -> 0. DPP ctrl 0x138 = wave_shr:1.
__device__ __forceinline__ float dpp_shr1_f(float x) {
    return __int_as_float(
        __builtin_amdgcn_update_dpp(0, __float_as_int(x), 0x138, 0xf, 0xf, false));
}
__device__ __forceinline__ int dpp_shr1_i(int x) {
    return __builtin_amdgcn_update_dpp(0, x, 0x138, 0xf, 0xf, false);
}
// lane l -> value of lane l+1; lane 63 -> 0. DPP ctrl 0x130 = wave_shl:1.
__device__ __forceinline__ float dpp_shl1_f(float x) {
    return __int_as_float(
        __builtin_amdgcn_update_dpp(0, __float_as_int(x), 0x130, 0xf, 0xf, false));
}
__device__ __forceinline__ int dpp_shl1_i(int x) {
    return __builtin_amdgcn_update_dpp(0, x, 0x130, 0xf, 0xf, false);
}

struct G { float pb, p1, p3, p5, p7; };  // RAW lds values (EPSF added at use)

__launch_bounds__(128, 1)
__global__ void ctc_loss_kernel(const int* __restrict__ y_true,
                                const float* __restrict__ y_pred,
                                float* __restrict__ out) {
    const int b = blockIdx.x;
    const int tid = threadIdx.x;
    const int w = __builtin_amdgcn_readfirstlane(tid >> 6);  // 0=fwd, 1=bwd
    const int l = tid & 63;

    __shared__ float ring[2][4][CH_ * C_];  // 2 waves x 4 bufs x 16x128 = 64 KB

    const int* __restrict__ lab = y_true + b * L_;
    const int4 lv = *(const int4*)(lab + 4 * l);   // labels 4l..4l+3
    const int e1 = lv.x, e3 = lv.y, e5 = lv.z, e7 = lv.w;
    const int em1 = (l > 0) ? lab[4 * l - 1] : -1;
    const float m1f = ((l > 0) && (e1 != em1)) ? 1.0f : 0.0f;  // skip gates
    const float m3f = (e3 != e1) ? 1.0f : 0.0f;
    const float m5f = (e5 != e3) ? 1.0f : 0.0f;
    const float m7f = (e7 != e5) ? 1.0f : 0.0f;
    const float m8f = (l == 63) ? 1.0f : 0.0f;     // state-512 coupling gate

    const float* __restrict__ base = y_pred + (size_t)b * (T_ * C_);

    // Column base pointers, addrspace(3): 32-bit LDS byte addresses in VGPRs.
    lds_f* const lbase = (lds_f*)&ring[0][0][0];
    const int relem = w * 8192;                    // wave's ring base, elems
    lds_f* const pB = lbase + relem + BLANK_;
    lds_f* const p1p = lbase + relem + e1;
    lds_f* const p3p = lbase + relem + e3;
    lds_f* const p5p = lbase + relem + e5;
    lds_f* const p7p = lbase + relem + e7;

    G g[4];  // lookahead-4 slots; slot index always compile-time
    auto fill = [&](int slot, int off) {  // off = BYTES: buf*8192 + row*512
        DSR(g[slot].pb, pB, off);
        DSR(g[slot].p1, p1p, off);
        DSR(g[slot].p3, p3p, off);
        DSR(g[slot].p5, p5p, off);
        DSR(g[slot].p7, p7p, off);
    };

    auto issue_chunk = [&](int t0, int buf) {
        const float* gp = base + (size_t)t0 * C_ + 4 * l;  // lane*16B
        float* d = &ring[w][buf][0];
#pragma unroll
        for (int i = 0; i < 8; ++i)
            gl2lds16(gp + i * 256, d + i * 256);
    };

    // linear mantissas at lane-local scale 2^E
    float a0 = 0.f, a1 = 0.f, a2 = 0.f, a3 = 0.f, a4 = 0.f,
          a5 = 0.f, a6 = 0.f, a7 = 0.f, a8 = 0.f;
    int E = SENT_;
    float upscale = 1.0f;  // 2^(E_nbr - E), fixed within a 4-step window

    // ---------------- forward machinery (wave 0) ----------------
    auto step = [&](const G& q) {
        const float pb = q.pb + EPSF, p1 = q.p1 + EPSF, p3 = q.p3 + EPSF,
                    p5 = q.p5 + EPSF, p7 = q.p7 + EPSF;
        const float up = dpp_shr1_f(a7) * upscale;  // state 8l-1, rescaled
        const float n0 = (a0 + up) * pb;
        const float n1 = fmaf(m1f, up, a0 + a1) * p1;
        const float n2 = (a1 + a2) * pb;
        const float n3 = fmaf(m3f, a1, a2 + a3) * p3;
        const float n4 = (a3 + a4) * pb;
        const float n5 = fmaf(m5f, a3, a4 + a5) * p5;
        const float n6 = (a5 + a6) * pb;
        const float n7 = fmaf(m7f, a5, a6 + a7) * p7;
        const float n8 = fmaf(m8f, a7, a8) * pb;    // state 512
        a0 = n0; a1 = n1; a2 = n2; a3 = n3; a4 = n4;
        a5 = n5; a6 = n6; a7 = n7; a8 = n8;
    };

    auto boundary = [&]() {
        float mx = fmaxf(fmaxf(fmaxf(a0, a1), fmaxf(a2, a3)),
                         fmaxf(fmaxf(a4, a5), fmaxf(a6, a7)));
        mx = fmaxf(mx, a8);
        const bool z = (mx == 0.0f);
        const int e = (int)(__float_as_uint(mx) >> 23) - 127;
        const float s = z ? 1.0f : __uint_as_float((unsigned)(127 - e) << 23);
        a0 *= s; a1 *= s; a2 *= s; a3 *= s; a4 *= s;
        a5 *= s; a6 *= s; a7 *= s; a8 *= s;
        E = z ? SENT_ : (E + e);
        int upE = dpp_shr1_i(E);
        if (l == 0) upE = SENT_;
        if (E == SENT_) E = upE;            // adopt neighbor scale (exact)
        int d = upE - E;
        d = min(max(d, -126), 120);
        upscale = __uint_as_float((unsigned)(d + 127) << 23);
    };

    // Per step: counted lgkm wait (20 asm reads in flight, oldest 5 must
    // land); ladder tightens in the final chunk as fills stop.
    auto run_chunk = [&](int bc, int bn, int jstart, bool last) {
#pragma unroll
        for (int j = 0; j < CH_; ++j) {
            if (j == 0 && jstart) continue;      // folds at compile time
            if (!last || j <= 12) { WAIT_LGKM(15); }
            else if (j == 13)     { WAIT_LGKM(10); }
            else if (j == 14)     { WAIT_LGKM(5); }
            else                  { WAIT_LGKM(0); }
            step(g[j & 3]);
            if (!last || j < 12) {
                const int off = (j < 12) ? (bc * 8192 + (j + 4) * 512)
                                         : (bn * 8192 + (j - 12) * 512);
                fill(j & 3, off);
            }
            if ((j & 3) == 3) boundary();
        }
    };

    // ---------------- backward machinery (wave 1) ----------------
    auto stepb = [&](const G& q) {
        const float pb = q.pb + EPSF, p1 = q.p1 + EPSF, p3 = q.p3 + EPSF,
                    p5 = q.p5 + EPSF, p7 = q.p7 + EPSF;
        const float d0 = a0 * pb, d1 = a1 * p1, d2 = a2 * pb,
                    d3 = a3 * p3, d4 = a4 * pb, d5 = a5 * p5,
                    d6 = a6 * pb, d7 = a7 * p7, d8 = a8 * pb;
        const float u = fmaf(m1f, d1, d0);          // exported to lane l-1
        const float dn = dpp_shl1_f(u) * upscale;   // lane l+1's u, rescaled
        a0 = d0 + d1;
        a1 = fmaf(m3f, d3, d1 + d2);
        a2 = d2 + d3;
        a3 = fmaf(m5f, d5, d3 + d4);
        a4 = d4 + d5;
        a5 = fmaf(m7f, d7, d5 + d6);
        a6 = d6 + d7;
        a7 = fmaf(m8f, d8, d7 + dn);                // state 511 (+512 on l=63)
        a8 = d8;                                    // state 512
    };

    auto boundaryb = [&]() {
        float mx = fmaxf(fmaxf(fmaxf(a0, a1), fmaxf(a2, a3)),
                         fmaxf(fmaxf(a4, a5), fmaxf(a6, a7)));
        mx = fmaxf(mx, a8);
        const bool z = (mx == 0.0f);
        const int e = (int)(__float_as_uint(mx) >> 23) - 127;
        const float s = z ? 1.0f : __uint_as_float((unsigned)(127 - e) << 23);
        a0 *= s; a1 *= s; a2 *= s; a3 *= s; a4 *= s;
        a5 *= s; a6 *= s; a7 *= s; a8 *= s;
        E = z ? SENT_ : (E + e);
        int upE = dpp_shl1_i(E);            // neighbor is lane l+1
        if (l == 63) upE = SENT_;
        if (E == SENT_) E = upE;
        int d = upE - E;
        d = min(max(d, -126), 120);
        upscale = __uint_as_float((unsigned)(d + 127) << 23);
    };

    // step j consumes row 15-j of bc (slot j&3); refills with row 15-(j+4).
    auto run_chunkb = [&](int bc, int bn, bool last) {
#pragma unroll
        for (int j = 0; j < CH_; ++j) {
            if (!last || j <= 12) { WAIT_LGKM(15); }
            else if (j == 13)     { WAIT_LGKM(10); }
            else if (j == 14)     { WAIT_LGKM(5); }
            else                  { WAIT_LGKM(0); }
            stepb(g[j & 3]);
            if (!last || j < 12) {
                const int off = (j < 12) ? (bc * 8192 + (11 - j) * 512)
                                         : (bn * 8192 + (27 - j) * 512);
                fill(j & 3, off);
            }
            if ((j & 3) == 3) boundaryb();
        }
    };

    if (w == 0) {
        // ======== forward: chunks 0..63 (t = 0..1023) ========
        issue_chunk(0, 0);
        issue_chunk(CH_, 1);
        issue_chunk(2 * CH_, 2);

        WAIT_VM(8);                        // chunks 0,1 landed; 2 in flight
        issue_chunk(3 * CH_, 3);
        {
            const float* rbf = &ring[0][0][0];
            if (l == 0) { a0 = rbf[BLANK_] + EPSF; a1 = rbf[e1] + EPSF; E = 0; }
        }
        boundary();                        // seeds lane1's adoption of E
        fill(1, 1 * 512);                  // rows 1..4 for slots 1,2,3,0
        fill(2, 2 * 512);
        fill(3, 3 * 512);
        fill(0, 4 * 512);
        run_chunk(0, 1, 1, false);
        WAIT_VM(8); issue_chunk(4 * CH_, 0); run_chunk(1, 2, 0, false);
        WAIT_VM(8); issue_chunk(5 * CH_, 1); run_chunk(2, 3, 0, false);
        WAIT_VM(8); issue_chunk(6 * CH_, 2); run_chunk(3, 0, 0, false);

#pragma unroll 1
        for (int m = 1; m <= 14; ++m) {    // chunks 4..59
            const int c = 4 * m;
            WAIT_VM(8); issue_chunk((c + 3) * CH_, 3); run_chunk(0, 1, 0, false);
            WAIT_VM(8); issue_chunk((c + 4) * CH_, 0); run_chunk(1, 2, 0, false);
            WAIT_VM(8); issue_chunk((c + 5) * CH_, 1); run_chunk(2, 3, 0, false);
            WAIT_VM(8); issue_chunk((c + 6) * CH_, 2); run_chunk(3, 0, 0, false);
        }

        WAIT_VM(8); issue_chunk(63 * CH_, 3); run_chunk(0, 1, 0, false);
        WAIT_VM(8);                        // 62 landed; 63 in flight
        run_chunk(1, 2, 0, false);
        WAIT_VM(0);                        // 63 landed
        run_chunk(2, 3, 0, false);
        run_chunk(3, 3, 0, true);
        // a0..a8, E now hold alpha_{1023}
    } else {
        // ======== backward: chunks 127..64 (t = 2047..1024), order q ========
        auto issq = [&](int q, int buf) { issue_chunk((127 - q) * CH_, buf); };
        issq(0, 0); issq(1, 1); issq(2, 2);

        WAIT_VM(8);
        issq(3, 3);
        if (l == 63) { a7 = 1.0f; a8 = 1.0f; E = 0; }  // c_2048 = f
        boundaryb();                       // seeds lane62's adoption of E
        // slots 0..3 <- q=0..3 (rows 15,14,13,12 of buf 0)
        fill(0, 15 * 512); fill(1, 14 * 512); fill(2, 13 * 512); fill(3, 12 * 512);
        run_chunkb(0, 1, false);
        WAIT_VM(8); issq(4, 0); run_chunkb(1, 2, false);
        WAIT_VM(8); issq(5, 1); run_chunkb(2, 3, false);
        WAIT_VM(8); issq(6, 2); run_chunkb(3, 0, false);

#pragma unroll 1
        for (int m = 1; m <= 14; ++m) {
            const int c = 4 * m;
            WAIT_VM(8); issq(c + 3, 3); run_chunkb(0, 1, false);
            WAIT_VM(8); issq(c + 4, 0); run_chunkb(1, 2, false);
            WAIT_VM(8); issq(c + 5, 1); run_chunkb(2, 3, false);
            WAIT_VM(8); issq(c + 6, 2); run_chunkb(3, 0, false);
        }

        WAIT_VM(8); issq(63, 3); run_chunkb(0, 1, false);
        WAIT_VM(8);
        run_chunkb(1, 2, false);
        WAIT_VM(0);
        run_chunkb(2, 3, false);
        run_chunkb(3, 3, true);
        // a0..a8, E now hold c_{1024}; export via own ring (drained)
        float* xf = &ring[1][0][0];
        xf[0 * 64 + l] = a0; xf[1 * 64 + l] = a1; xf[2 * 64 + l] = a2;
        xf[3 * 64 + l] = a3; xf[4 * 64 + l] = a4; xf[5 * 64 + l] = a5;
        xf[6 * 64 + l] = a6; xf[7 * 64 + l] = a7; xf[8 * 64 + l] = a8;
        ((int*)xf)[9 * 64 + l] = E;
    }

    __syncthreads();

    if (w == 0) {
        // p = <alpha_{1023}, c_{1024}>: lane dot then 64-lane logsumexp.
        const float* xf = &ring[1][0][0];
        float sd = a0 * xf[0 * 64 + l];
        sd = fmaf(a1, xf[1 * 64 + l], sd);
        sd = fmaf(a2, xf[2 * 64 + l], sd);
        sd = fmaf(a3, xf[3 * 64 + l], sd);
        sd = fmaf(a4, xf[4 * 64 + l], sd);
        sd = fmaf(a5, xf[5 * 64 + l], sd);
        sd = fmaf(a6, xf[6 * 64 + l], sd);
        sd = fmaf(a7, xf[7 * 64 + l], sd);
        sd = fmaf(a8, xf[8 * 64 + l], sd);
        const int E2 = ((const int*)xf)[9 * 64 + l];
        const bool nz = (sd > 0.0f);
        int Es = nz ? (E + E2) : SENT_;
        int M = Es;
#pragma unroll
        for (int o = 32; o; o >>= 1) M = max(M, __shfl_xor(M, o));
        int d = Es - M;
        d = max(d, -126);
        float val = nz ? sd * __uint_as_float((unsigned)(d + 127) << 23) : 0.0f;
#pragma unroll
        for (int o = 32; o; o >>= 1) val += __shfl_xor(val, o);
        if (l == 0) out[b] = -(__logf(val) + (float)M * LN2F);
    }
}

extern "C" void kernel_launch(void* const* d_in, const int* in_sizes, int n_in,
                              void* d_out, int out_size, void* d_ws, size_t ws_size,
                              hipStream_t stream) {
    const int* y_true = (const int*)d_in[0];
    const float* y_pred = (const float*)d_in[1];
    float* out = (float*)d_out;
    ctc_loss_kernel<<<B_, 128, 0, stream>>>(y_true, y_pred, out);
}